// Round 7
// baseline (2205.634 us; speedup 1.0000x reference)
//
#include <hip/hip_runtime.h>
#include <hip/hip_bf16.h>

// Problem constants
#define B_    1024
#define DIMC  64      // DIM
#define T_    255     // S-1 sequence steps
#define H_    128
#define CS_   500
#define S_    256

#define GROWS 16              // batch rows per group
#define MROWS 32              // rows per block = 2 async groups
#define NBLK  (B_ / MROWS)    // 32 blocks
#define NTHR  1024            // 16 waves: waves 0-7 = group 0, 8-15 = group 1
#define TCH   8               // timesteps staged per chunk
#define XSX   132             // x LDS row stride (shorts)
#define XSH   136             // h LDS row stride (shorts)

// LDS layout (bytes):
//   x: 2 groups x 2 bufs x TCH x 16 x XSX x 2 = 135,168   @ 0
//   h: 2 groups x 2 bufs x 16 x XSH x 2       =  17,408   @ 135,168
//   sidx: 32 x 64 x 4                          =   8,192   @ 152,576
//   group barrier counters                     =     256   @ 160,768
#define XBYTES  (2 * TCH * GROWS * XSX * 2)   // per-group x region: 67,584
#define HBYTES  (2 * GROWS * XSH * 2)         // per-group h region: 8,704
#define OFF_H   (2 * XBYTES)                  // 135,168
#define OFF_IDX (OFF_H + 2 * HBYTES)          // 152,576
#define OFF_CTR (OFF_IDX + 8192)              // 160,768
#define SMEMB   (OFF_CTR + 256)               // 161,024 <= 163,840

typedef __attribute__((ext_vector_type(8))) short bf16x8;
typedef __attribute__((ext_vector_type(4))) float f32x4;

__device__ __forceinline__ unsigned short f2bf(float f) {
    unsigned int u = __builtin_bit_cast(unsigned int, f);
    return (unsigned short)((u + 0x7FFFu + ((u >> 16) & 1u)) >> 16);
}
__device__ __forceinline__ float fast_rcp(float x) { return __builtin_amdgcn_rcpf(x); }
__device__ __forceinline__ float sigm(float x)   { float e = __expf(-x); return fast_rcp(1.0f + e); }
__device__ __forceinline__ float tanh_f(float x) { float e = __expf(2.0f * x); return 1.0f - 2.0f * fast_rcp(1.0f + e); }
__device__ __forceinline__ float leaky(float x)  { return x > 0.0f ? x : 0.01f * x; }
__device__ __forceinline__ int   imin(int a, int b) { return a < b ? a : b; }

// Group-local spin barrier: monotone counter, 8 waves per group.
// lgkmcnt(0) before arrival ensures this wave's LDS writes are visible.
__device__ __forceinline__ void gbar(int* ctr, int& myph, int lane) {
    asm volatile("s_waitcnt lgkmcnt(0)" ::: "memory");
    myph += 8;
    if (lane == 0)
        __hip_atomic_fetch_add(ctr, 1, __ATOMIC_RELAXED, __HIP_MEMORY_SCOPE_WORKGROUP);
    while (__hip_atomic_load(ctr, __ATOMIC_RELAXED, __HIP_MEMORY_SCOPE_WORKGROUP) < myph)
        __builtin_amdgcn_s_sleep(1);
    asm volatile("" ::: "memory");
}

// Epilogue LDS layout (dword offsets; all < OFF_IDX/4, x/h regions dead)
#define OW1 0        // W1 padded 64 x 129
#define OW2 8256     // W2 padded 32 x 65
#define OW3 10336    // W3 padded 16 x 33
#define OWL 10864    // W_last padded 64 x 81
#define OHF 16048    // h fp32, 32 x 128
#define OS1 20144    // s1 per wave 16 x 64
#define OS2 21168    // s2 per wave 16 x 32
#define OS3 21680    // s3 per wave 16 x 16
#define OSL 21936    // last per wave 16 x 64  (ends 22,960 dw = 91,840 B)

__global__ __launch_bounds__(NTHR, 2)
void gru_fused(const float* __restrict__ x, const int* __restrict__ snippet,
               const float* __restrict__ slist,
               const float* __restrict__ W_ih, const float* __restrict__ W_hh,
               const float* __restrict__ b_ih, const float* __restrict__ b_hh,
               const float* __restrict__ W1, const float* __restrict__ b1,
               const float* __restrict__ W2, const float* __restrict__ b2,
               const float* __restrict__ W3, const float* __restrict__ b3,
               const float* __restrict__ Wl, const float* __restrict__ bl,
               float* __restrict__ out)
{
    __shared__ __attribute__((aligned(16))) unsigned char smem[SMEMB];
    int* sidx = (int*)(smem + OFF_IDX);                      // [32*64]

    const int tid   = threadIdx.x;
    const int bblk  = blockIdx.x * MROWS;
    const int lane  = tid & 63;
    const int wv    = tid >> 6;          // 0..15
    const int gid   = wv >> 3;           // group 0/1
    const int wv8   = wv & 7;            // wave within group
    const int utid  = tid & 511;         // thread within group
    const int l15   = lane & 15;
    const int l4    = lane >> 4;
    const int bbase = bblk + gid * GROWS;

    unsigned short* shx_g = (unsigned short*)(smem + gid * XBYTES);
    unsigned short* shh_g = (unsigned short*)(smem + OFF_H + gid * HBYTES);
    int* sidx_g = sidx + gid * GROWS * DIMC;
    int* ctr    = (int*)(smem + OFF_CTR) + gid * 32;

    // ---- snippet indices (whole block), zero h, zero barrier ctrs ----
    for (int i = tid; i < MROWS * DIMC; i += NTHR)
        sidx[i] = snippet[bblk * DIMC + i];
    for (int i = tid; i < 2 * 2 * GROWS * XSH; i += NTHR)
        ((unsigned short*)(smem + OFF_H))[i] = 0;
    if (tid < 2) *((int*)(smem + OFF_CTR) + tid * 32) = 0;

    // ---- weight B-fragments in registers (96 VGPR), per group-wave ----
    bf16x8 wih[3][4], whh[3][4];
    {
        const int g = (wv8 << 4) + l15;
#pragma unroll
        for (int gt = 0; gt < 3; ++gt) {
#pragma unroll
            for (int kb = 0; kb < 4; ++kb) {
                const float* p1 = W_ih + (size_t)(gt * 128 + g) * 128 + kb * 32 + (l4 << 3);
                const float* p2 = W_hh + (size_t)(gt * 128 + g) * 128 + kb * 32 + (l4 << 3);
                f32x4 a0, a1, c0, c1;
                __builtin_memcpy(&a0, p1, 16); __builtin_memcpy(&a1, p1 + 4, 16);
                __builtin_memcpy(&c0, p2, 16); __builtin_memcpy(&c1, p2 + 4, 16);
                bf16x8 a, c;
#pragma unroll
                for (int e = 0; e < 4; ++e) {
                    a[e] = (short)f2bf(a0[e]); a[e + 4] = (short)f2bf(a1[e]);
                    c[e] = (short)f2bf(c0[e]); c[e + 4] = (short)f2bf(c1[e]);
                }
                wih[gt][kb] = a; whh[gt][kb] = c;
            }
        }
    }
    const int jj = (wv8 << 4) + l15;
    const float bias_r = b_ih[jj]       + b_hh[jj];
    const float bias_z = b_ih[128 + jj] + b_hh[128 + jj];
    const float bxn    = b_ih[256 + jj];
    const float bhn    = b_hh[256 + jj];

    __syncthreads();   // sidx ready, h zeroed, ctrs zeroed

    // ---- staging (per group, 512 thr): 2 units/thread; unit = (row, even k0) ----
    int rowu[2], k0u[2], isx[2];
    const float* pa[2]; const float* pb[2];
#pragma unroll
    for (int un = 0; un < 2; ++un) {
        int u  = utid + un * 512;
        int r  = u >> 6;
        int k0 = (u & 63) << 1;
        rowu[un] = r; k0u[un] = k0;
        if (k0 < DIMC) {
            isx[un] = 1;
            pa[un] = x + ((size_t)(bbase + r) * DIMC + k0) * T_;
            pb[un] = pa[un] + T_;
        } else {
            isx[un] = 0;
            int d = k0 - DIMC;
            pa[un] = slist + ((size_t)d       * CS_ + sidx_g[(r << 6) + d])     * S_;
            pb[un] = slist + ((size_t)(d + 1) * CS_ + sidx_g[(r << 6) + d + 1]) * S_;
        }
    }

    f32x4 sa[2][2], sb[2][2];   // 8 timesteps x 2 k per thread

    auto issue = [&](int t0) {
#pragma unroll
        for (int un = 0; un < 2; ++un) {
            if (isx[un] && t0 + TCH - 1 > T_ - 1) {   // x tail clamp (t0 = 248 only)
#pragma unroll
                for (int g = 0; g < 2; ++g) {
                    f32x4 va, vb;
#pragma unroll
                    for (int e = 0; e < 4; ++e) {
                        int tt = imin(t0 + g * 4 + e, T_ - 1);
                        va[e] = pa[un][tt]; vb[e] = pb[un][tt];
                    }
                    sa[un][g] = va; sb[un][g] = vb;
                }
            } else {
#pragma unroll
                for (int g = 0; g < 2; ++g) {
                    f32x4 va, vb;
                    __builtin_memcpy(&va, pa[un] + t0 + g * 4, 16);
                    __builtin_memcpy(&vb, pb[un] + t0 + g * 4, 16);
                    sa[un][g] = va; sb[un][g] = vb;
                }
            }
        }
    };

    auto commit = [&](int buf) {
        unsigned short* dst = shx_g + buf * (TCH * GROWS * XSX);
#pragma unroll
        for (int un = 0; un < 2; ++un) {
#pragma unroll
            for (int g = 0; g < 2; ++g) {
#pragma unroll
                for (int e = 0; e < 4; ++e) {
                    int t = g * 4 + e;
                    unsigned pk = (unsigned)f2bf(sa[un][g][e]) | ((unsigned)f2bf(sb[un][g][e]) << 16);
                    *(unsigned*)&dst[(t * GROWS + rowu[un]) * XSX + k0u[un]] = pk;
                }
            }
        }
    };

    int cur = 0;
    int myph = 0;
    float hprev[4] = {0.f, 0.f, 0.f, 0.f};
    const f32x4 Z = {0.f, 0.f, 0.f, 0.f};

    // xg: batch x-part of gates for up to 4 steps (independent MFMAs)
    auto xg_phase = [&](int buf, int tb, int nt, f32x4* xr, f32x4* xz, f32x4* xn) {
        const unsigned short* base = shx_g + buf * (TCH * GROWS * XSX);
#pragma unroll
        for (int tt = 0; tt < 4; ++tt) {
            if (tt >= nt) break;
            const unsigned short* xp = base + ((tb + tt) * GROWS + l15) * XSX + (l4 << 3);
            bf16x8 a[4];
#pragma unroll
            for (int kb = 0; kb < 4; ++kb) a[kb] = *(const bf16x8*)(xp + kb * 32);
            f32x4 r = Z, z = Z, n = Z;
#pragma unroll
            for (int kb = 0; kb < 4; ++kb) {
                r = __builtin_amdgcn_mfma_f32_16x16x32_bf16(a[kb], wih[0][kb], r, 0, 0, 0);
                z = __builtin_amdgcn_mfma_f32_16x16x32_bf16(a[kb], wih[1][kb], z, 0, 0, 0);
                n = __builtin_amdgcn_mfma_f32_16x16x32_bf16(a[kb], wih[2][kb], n, 0, 0, 0);
            }
            xr[tt] = r; xz[tt] = z; xn[tt] = n;
        }
    };

    auto recur = [&](f32x4 xr, f32x4 xz, f32x4 xn) {
        const unsigned short* hp = shh_g + cur * (GROWS * XSH) + l15 * XSH + (l4 << 3);
        bf16x8 h0 = *(const bf16x8*)(hp);
        bf16x8 h1 = *(const bf16x8*)(hp + 32);
        bf16x8 h2 = *(const bf16x8*)(hp + 64);
        bf16x8 h3 = *(const bf16x8*)(hp + 96);
        f32x4 arA = __builtin_amdgcn_mfma_f32_16x16x32_bf16(h0, whh[0][0], xr, 0, 0, 0);
        f32x4 azA = __builtin_amdgcn_mfma_f32_16x16x32_bf16(h0, whh[1][0], xz, 0, 0, 0);
        f32x4 anA = __builtin_amdgcn_mfma_f32_16x16x32_bf16(h0, whh[2][0], Z,  0, 0, 0);
        f32x4 arB = __builtin_amdgcn_mfma_f32_16x16x32_bf16(h2, whh[0][2], Z,  0, 0, 0);
        f32x4 azB = __builtin_amdgcn_mfma_f32_16x16x32_bf16(h2, whh[1][2], Z,  0, 0, 0);
        f32x4 anB = __builtin_amdgcn_mfma_f32_16x16x32_bf16(h2, whh[2][2], Z,  0, 0, 0);
        arA = __builtin_amdgcn_mfma_f32_16x16x32_bf16(h1, whh[0][1], arA, 0, 0, 0);
        azA = __builtin_amdgcn_mfma_f32_16x16x32_bf16(h1, whh[1][1], azA, 0, 0, 0);
        anA = __builtin_amdgcn_mfma_f32_16x16x32_bf16(h1, whh[2][1], anA, 0, 0, 0);
        arB = __builtin_amdgcn_mfma_f32_16x16x32_bf16(h3, whh[0][3], arB, 0, 0, 0);
        azB = __builtin_amdgcn_mfma_f32_16x16x32_bf16(h3, whh[1][3], azB, 0, 0, 0);
        anB = __builtin_amdgcn_mfma_f32_16x16x32_bf16(h3, whh[2][3], anB, 0, 0, 0);
        unsigned short* hw = shh_g + (cur ^ 1) * (GROWS * XSH);
#pragma unroll
        for (int q = 0; q < 4; ++q) {
            float r = sigm(arA[q] + arB[q] + bias_r);
            float z = sigm(azA[q] + azB[q] + bias_z);
            float n = tanh_f(xn[q] + bxn + r * (anA[q] + anB[q] + bhn));
            float hn = (1.0f - z) * n + z * hprev[q];
            hprev[q] = hn;
            hw[((l4 << 2) + q) * XSH + jj] = f2bf(hn);
        }
        gbar(ctr, myph, lane);
        cur ^= 1;
    };

    // ---- prologue: stage chunk 0 ----
    issue(0);
    commit(0);
    gbar(ctr, myph, lane);

    // ---- main: 31 full chunks of 8 steps (t = 0..247), per group, async ----
    for (int c = 0; c < 31; ++c) {
        issue((c + 1) * TCH);           // prefetch; gbar never drains vmcnt
        const int bx = c & 1;
        f32x4 xr[4], xz[4], xn[4];
        xg_phase(bx, 0, 4, xr, xz, xn);
#pragma unroll
        for (int tt = 0; tt < 4; ++tt) recur(xr[tt], xz[tt], xn[tt]);
        xg_phase(bx, 4, 4, xr, xz, xn);
#pragma unroll
        for (int tt = 0; tt < 4; ++tt) recur(xr[tt], xz[tt], xn[tt]);
        commit((c + 1) & 1);
        gbar(ctr, myph, lane);
    }
    // ---- tail chunk: 7 steps (t = 248..254), buffer 1 ----
    {
        f32x4 xr[4], xz[4], xn[4];
        xg_phase(1, 0, 4, xr, xz, xn);
#pragma unroll
        for (int tt = 0; tt < 4; ++tt) recur(xr[tt], xz[tt], xn[tt]);
        xg_phase(1, 4, 3, xr, xz, xn);
#pragma unroll
        for (int tt = 0; tt < 3; ++tt) recur(xr[tt], xz[tt], xn[tt]);
    }

    __syncthreads();   // both groups done; x/h regions now dead

    // ================= fused MLP epilogue (LDS-resident weights) =================
    float* wl = (float*)smem;   // sidx region (>= OFF_IDX) preserved

    for (int i = tid; i < 8192; i += NTHR) wl[OW1 + (i >> 7) * 129 + (i & 127)] = W1[i];
    for (int i = tid; i < 2048; i += NTHR) wl[OW2 + (i >> 6) * 65  + (i & 63)]  = W2[i];
    for (int i = tid; i < 512;  i += NTHR) wl[OW3 + (i >> 5) * 33  + (i & 31)]  = W3[i];
    for (int i = tid; i < 5120; i += NTHR) wl[OWL + (i / 80) * 81  + (i % 80)]  = Wl[i];
#pragma unroll
    for (int q = 0; q < 4; ++q)
        wl[OHF + (gid * GROWS + (l4 << 2) + q) * 128 + jj] = hprev[q];
    __syncthreads();

    // wave wv handles block rows 2*wv, 2*wv+1  (wv 0..15 -> rows 0..31)
    for (int mloc = 0; mloc < 2; ++mloc) {
        const int m = (wv << 1) + mloc;
        {
            float s = b1[lane];
            const float* w = wl + OW1 + lane * 129;
            for (int k = 0; k < 128; ++k) s += wl[OHF + m * 128 + k] * w[k];
            wl[OS1 + wv * 64 + lane] = leaky(s);
        }
        __syncthreads();
        if (lane < 32) {
            float s = b2[lane];
            const float* w = wl + OW2 + lane * 65;
            for (int k = 0; k < 64; ++k) s += wl[OS1 + wv * 64 + k] * w[k];
            wl[OS2 + wv * 32 + lane] = leaky(s);
        } else {
            int d = lane - 32;
            wl[OSL + wv * 64 + d]      = slist[((size_t)d        * CS_ + sidx[(m << 6) + d])      * S_ + (S_ - 1)];
            wl[OSL + wv * 64 + d + 32] = slist[((size_t)(d + 32) * CS_ + sidx[(m << 6) + d + 32]) * S_ + (S_ - 1)];
        }
        __syncthreads();
        if (lane < 16) {
            float s = b3[lane];
            const float* w = wl + OW3 + lane * 33;
            for (int k = 0; k < 32; ++k) s += wl[OS2 + wv * 32 + k] * w[k];
            wl[OS3 + wv * 16 + lane] = leaky(s);
        }
        __syncthreads();
        {
            float s = bl[lane];
            const float* w = wl + OWL + lane * 81;
#pragma unroll
            for (int i = 0; i < 16; ++i) s += wl[OS3 + wv * 16 + i] * w[i];
            for (int d = 0; d < 64; ++d) s += wl[OSL + wv * 64 + d] * w[16 + d];
            out[(size_t)(bblk + m) * DIMC + lane] = leaky(s);
        }
        __syncthreads();
    }
}

extern "C" void kernel_launch(void* const* d_in, const int* in_sizes, int n_in,
                              void* d_out, int out_size, void* d_ws, size_t ws_size,
                              hipStream_t stream) {
    (void)in_sizes; (void)n_in; (void)out_size; (void)d_ws; (void)ws_size;
    const float* x       = (const float*)d_in[0];
    const int*   snippet = (const int*)  d_in[1];
    const float* slist   = (const float*)d_in[2];
    const float* W_ih    = (const float*)d_in[3];
    const float* W_hh    = (const float*)d_in[4];
    const float* b_ih    = (const float*)d_in[5];
    const float* b_hh    = (const float*)d_in[6];
    const float* W1      = (const float*)d_in[7];
    const float* b1      = (const float*)d_in[8];
    const float* W2      = (const float*)d_in[9];
    const float* b2      = (const float*)d_in[10];
    const float* W3      = (const float*)d_in[11];
    const float* b3      = (const float*)d_in[12];
    const float* Wl      = (const float*)d_in[13];
    const float* bl      = (const float*)d_in[14];
    float* out = (float*)d_out;

    hipLaunchKernelGGL(gru_fused, dim3(NBLK), dim3(NTHR), 0, stream,
                       x, snippet, slist, W_ih, W_hh, b_ih, b_hh,
                       W1, b1, W2, b2, W3, b3, Wl, bl, out);
}

// Round 8
// 2204.809 us; speedup vs baseline: 1.0004x; 1.0004x over previous
//
#include <hip/hip_runtime.h>
#include <hip/hip_bf16.h>

// Problem constants
#define B_    1024
#define DIMC  64      // DIM
#define T_    255     // S-1 sequence steps
#define H_    128
#define CS_   500
#define S_    256

#define GROWS 16              // batch rows per group
#define MROWS 32              // rows per block = 2 async groups
#define NBLK  (B_ / MROWS)    // 32 blocks
#define NTHR  1024            // 16 waves: waves 0-7 = group 0, 8-15 = group 1
#define TCH   8               // timesteps staged per chunk
#define XSX   132             // x LDS row stride (shorts)
#define XSH   136             // h LDS row stride (shorts)

// EMPIRICAL launch_bounds law (R2/R4/R6/R7): VGPR cap = 512 / (arg2 * wavesPerSIMDperBlock).
// (1024,1): 4 waves/SIMD -> 128 VGPR cap, 1 block/CU (we have 32 blocks for 256 CUs - fine).

// LDS layout (bytes):
//   x: 2 groups x 2 bufs x TCH x 16 x XSX x 2 = 135,168   @ 0
//   h: 2 groups x 2 bufs x 16 x XSH x 2       =  17,408   @ 135,168
//   sidx: 32 x 64 x 4                          =   8,192   @ 152,576
//   group barrier counters                     =     256   @ 160,768
#define XBYTES  (2 * TCH * GROWS * XSX * 2)   // per-group x region: 67,584
#define HBYTES  (2 * GROWS * XSH * 2)         // per-group h region: 8,704
#define OFF_H   (2 * XBYTES)                  // 135,168
#define OFF_IDX (OFF_H + 2 * HBYTES)          // 152,576
#define OFF_CTR (OFF_IDX + 8192)              // 160,768
#define SMEMB   (OFF_CTR + 256)               // 161,024 <= 163,840

typedef __attribute__((ext_vector_type(8))) short bf16x8;
typedef __attribute__((ext_vector_type(4))) float f32x4;

__device__ __forceinline__ unsigned short f2bf(float f) {
    unsigned int u = __builtin_bit_cast(unsigned int, f);
    return (unsigned short)((u + 0x7FFFu + ((u >> 16) & 1u)) >> 16);
}
__device__ __forceinline__ float fast_rcp(float x) { return __builtin_amdgcn_rcpf(x); }
__device__ __forceinline__ float sigm(float x)   { float e = __expf(-x); return fast_rcp(1.0f + e); }
__device__ __forceinline__ float tanh_f(float x) { float e = __expf(2.0f * x); return 1.0f - 2.0f * fast_rcp(1.0f + e); }
__device__ __forceinline__ float leaky(float x)  { return x > 0.0f ? x : 0.01f * x; }
__device__ __forceinline__ int   imin(int a, int b) { return a < b ? a : b; }

// Group-local spin barrier: monotone counter, 8 waves per group.
// lgkmcnt(0) before arrival ensures this wave's LDS writes are visible.
__device__ __forceinline__ void gbar(int* ctr, int& myph, int lane) {
    asm volatile("s_waitcnt lgkmcnt(0)" ::: "memory");
    myph += 8;
    if (lane == 0)
        __hip_atomic_fetch_add(ctr, 1, __ATOMIC_RELAXED, __HIP_MEMORY_SCOPE_WORKGROUP);
    while (__hip_atomic_load(ctr, __ATOMIC_RELAXED, __HIP_MEMORY_SCOPE_WORKGROUP) < myph)
        __builtin_amdgcn_s_sleep(1);
    asm volatile("" ::: "memory");
}

// Epilogue LDS layout (dword offsets; all < OFF_IDX/4, x/h regions dead)
#define OW1 0        // W1 padded 64 x 129
#define OW2 8256     // W2 padded 32 x 65
#define OW3 10336    // W3 padded 16 x 33
#define OWL 10864    // W_last padded 64 x 81
#define OHF 16048    // h fp32, 32 x 128
#define OS1 20144    // s1 per wave 16 x 64
#define OS2 21168    // s2 per wave 16 x 32
#define OS3 21680    // s3 per wave 16 x 16
#define OSL 21936    // last per wave 16 x 64  (ends 22,960 dw = 91,840 B)

__global__ __launch_bounds__(NTHR, 1)
void gru_fused(const float* __restrict__ x, const int* __restrict__ snippet,
               const float* __restrict__ slist,
               const float* __restrict__ W_ih, const float* __restrict__ W_hh,
               const float* __restrict__ b_ih, const float* __restrict__ b_hh,
               const float* __restrict__ W1, const float* __restrict__ b1,
               const float* __restrict__ W2, const float* __restrict__ b2,
               const float* __restrict__ W3, const float* __restrict__ b3,
               const float* __restrict__ Wl, const float* __restrict__ bl,
               float* __restrict__ out)
{
    __shared__ __attribute__((aligned(16))) unsigned char smem[SMEMB];
    int* sidx = (int*)(smem + OFF_IDX);                      // [32*64]

    const int tid   = threadIdx.x;
    const int bblk  = blockIdx.x * MROWS;
    const int lane  = tid & 63;
    const int wv    = tid >> 6;          // 0..15
    const int gid   = wv >> 3;           // group 0/1
    const int wv8   = wv & 7;            // wave within group
    const int utid  = tid & 511;         // thread within group
    const int l15   = lane & 15;
    const int l4    = lane >> 4;
    const int bbase = bblk + gid * GROWS;

    unsigned short* shx_g = (unsigned short*)(smem + gid * XBYTES);
    unsigned short* shh_g = (unsigned short*)(smem + OFF_H + gid * HBYTES);
    int* sidx_g = sidx + gid * GROWS * DIMC;
    int* ctr    = (int*)(smem + OFF_CTR) + gid * 32;

    // ---- snippet indices (whole block), zero h, zero barrier ctrs ----
    for (int i = tid; i < MROWS * DIMC; i += NTHR)
        sidx[i] = snippet[bblk * DIMC + i];
    for (int i = tid; i < 2 * 2 * GROWS * XSH; i += NTHR)
        ((unsigned short*)(smem + OFF_H))[i] = 0;
    if (tid < 2) *((int*)(smem + OFF_CTR) + tid * 32) = 0;

    // ---- weight B-fragments in registers (96 VGPR), per group-wave ----
    bf16x8 wih[3][4], whh[3][4];
    {
        const int g = (wv8 << 4) + l15;
#pragma unroll
        for (int gt = 0; gt < 3; ++gt) {
#pragma unroll
            for (int kb = 0; kb < 4; ++kb) {
                const float* p1 = W_ih + (size_t)(gt * 128 + g) * 128 + kb * 32 + (l4 << 3);
                const float* p2 = W_hh + (size_t)(gt * 128 + g) * 128 + kb * 32 + (l4 << 3);
                f32x4 a0, a1, c0, c1;
                __builtin_memcpy(&a0, p1, 16); __builtin_memcpy(&a1, p1 + 4, 16);
                __builtin_memcpy(&c0, p2, 16); __builtin_memcpy(&c1, p2 + 4, 16);
                bf16x8 a, c;
#pragma unroll
                for (int e = 0; e < 4; ++e) {
                    a[e] = (short)f2bf(a0[e]); a[e + 4] = (short)f2bf(a1[e]);
                    c[e] = (short)f2bf(c0[e]); c[e + 4] = (short)f2bf(c1[e]);
                }
                wih[gt][kb] = a; whh[gt][kb] = c;
            }
        }
    }
    const int jj = (wv8 << 4) + l15;
    const float bias_r = b_ih[jj]       + b_hh[jj];
    const float bias_z = b_ih[128 + jj] + b_hh[128 + jj];
    const float bxn    = b_ih[256 + jj];
    const float bhn    = b_hh[256 + jj];

    __syncthreads();   // sidx ready, h zeroed, ctrs zeroed

    // ---- staging (per group, 512 thr): 2 units/thread; unit = (row, even k0) ----
    int rowu[2], k0u[2], isx[2];
    const float* pa[2]; const float* pb[2];
#pragma unroll
    for (int un = 0; un < 2; ++un) {
        int u  = utid + un * 512;
        int r  = u >> 6;
        int k0 = (u & 63) << 1;
        rowu[un] = r; k0u[un] = k0;
        if (k0 < DIMC) {
            isx[un] = 1;
            pa[un] = x + ((size_t)(bbase + r) * DIMC + k0) * T_;
            pb[un] = pa[un] + T_;
        } else {
            isx[un] = 0;
            int d = k0 - DIMC;
            pa[un] = slist + ((size_t)d       * CS_ + sidx_g[(r << 6) + d])     * S_;
            pb[un] = slist + ((size_t)(d + 1) * CS_ + sidx_g[(r << 6) + d + 1]) * S_;
        }
    }

    f32x4 sa[2][2], sb[2][2];   // 8 timesteps x 2 k per thread

    auto issue = [&](int t0) {
#pragma unroll
        for (int un = 0; un < 2; ++un) {
            if (isx[un] && t0 + TCH - 1 > T_ - 1) {   // x tail clamp (t0 = 248 only)
#pragma unroll
                for (int g = 0; g < 2; ++g) {
                    f32x4 va, vb;
#pragma unroll
                    for (int e = 0; e < 4; ++e) {
                        int tt = imin(t0 + g * 4 + e, T_ - 1);
                        va[e] = pa[un][tt]; vb[e] = pb[un][tt];
                    }
                    sa[un][g] = va; sb[un][g] = vb;
                }
            } else {
#pragma unroll
                for (int g = 0; g < 2; ++g) {
                    f32x4 va, vb;
                    __builtin_memcpy(&va, pa[un] + t0 + g * 4, 16);
                    __builtin_memcpy(&vb, pb[un] + t0 + g * 4, 16);
                    sa[un][g] = va; sb[un][g] = vb;
                }
            }
        }
    };

    auto commit = [&](int buf) {
        unsigned short* dst = shx_g + buf * (TCH * GROWS * XSX);
#pragma unroll
        for (int un = 0; un < 2; ++un) {
#pragma unroll
            for (int g = 0; g < 2; ++g) {
#pragma unroll
                for (int e = 0; e < 4; ++e) {
                    int t = g * 4 + e;
                    unsigned pk = (unsigned)f2bf(sa[un][g][e]) | ((unsigned)f2bf(sb[un][g][e]) << 16);
                    *(unsigned*)&dst[(t * GROWS + rowu[un]) * XSX + k0u[un]] = pk;
                }
            }
        }
    };

    int cur = 0;
    int myph = 0;
    float hprev[4] = {0.f, 0.f, 0.f, 0.f};
    const f32x4 Z = {0.f, 0.f, 0.f, 0.f};

    // xg: batch x-part of gates for up to 4 steps (independent MFMAs)
    auto xg_phase = [&](int buf, int tb, int nt, f32x4* xr, f32x4* xz, f32x4* xn) {
        const unsigned short* base = shx_g + buf * (TCH * GROWS * XSX);
#pragma unroll
        for (int tt = 0; tt < 4; ++tt) {
            if (tt >= nt) break;
            const unsigned short* xp = base + ((tb + tt) * GROWS + l15) * XSX + (l4 << 3);
            bf16x8 a[4];
#pragma unroll
            for (int kb = 0; kb < 4; ++kb) a[kb] = *(const bf16x8*)(xp + kb * 32);
            f32x4 r = Z, z = Z, n = Z;
#pragma unroll
            for (int kb = 0; kb < 4; ++kb) {
                r = __builtin_amdgcn_mfma_f32_16x16x32_bf16(a[kb], wih[0][kb], r, 0, 0, 0);
                z = __builtin_amdgcn_mfma_f32_16x16x32_bf16(a[kb], wih[1][kb], z, 0, 0, 0);
                n = __builtin_amdgcn_mfma_f32_16x16x32_bf16(a[kb], wih[2][kb], n, 0, 0, 0);
            }
            xr[tt] = r; xz[tt] = z; xn[tt] = n;
        }
    };

    auto recur = [&](f32x4 xr, f32x4 xz, f32x4 xn) {
        const unsigned short* hp = shh_g + cur * (GROWS * XSH) + l15 * XSH + (l4 << 3);
        bf16x8 h0 = *(const bf16x8*)(hp);
        bf16x8 h1 = *(const bf16x8*)(hp + 32);
        bf16x8 h2 = *(const bf16x8*)(hp + 64);
        bf16x8 h3 = *(const bf16x8*)(hp + 96);
        f32x4 arA = __builtin_amdgcn_mfma_f32_16x16x32_bf16(h0, whh[0][0], xr, 0, 0, 0);
        f32x4 azA = __builtin_amdgcn_mfma_f32_16x16x32_bf16(h0, whh[1][0], xz, 0, 0, 0);
        f32x4 anA = __builtin_amdgcn_mfma_f32_16x16x32_bf16(h0, whh[2][0], Z,  0, 0, 0);
        f32x4 arB = __builtin_amdgcn_mfma_f32_16x16x32_bf16(h2, whh[0][2], Z,  0, 0, 0);
        f32x4 azB = __builtin_amdgcn_mfma_f32_16x16x32_bf16(h2, whh[1][2], Z,  0, 0, 0);
        f32x4 anB = __builtin_amdgcn_mfma_f32_16x16x32_bf16(h2, whh[2][2], Z,  0, 0, 0);
        arA = __builtin_amdgcn_mfma_f32_16x16x32_bf16(h1, whh[0][1], arA, 0, 0, 0);
        azA = __builtin_amdgcn_mfma_f32_16x16x32_bf16(h1, whh[1][1], azA, 0, 0, 0);
        anA = __builtin_amdgcn_mfma_f32_16x16x32_bf16(h1, whh[2][1], anA, 0, 0, 0);
        arB = __builtin_amdgcn_mfma_f32_16x16x32_bf16(h3, whh[0][3], arB, 0, 0, 0);
        azB = __builtin_amdgcn_mfma_f32_16x16x32_bf16(h3, whh[1][3], azB, 0, 0, 0);
        anB = __builtin_amdgcn_mfma_f32_16x16x32_bf16(h3, whh[2][3], anB, 0, 0, 0);
        unsigned short* hw = shh_g + (cur ^ 1) * (GROWS * XSH);
#pragma unroll
        for (int q = 0; q < 4; ++q) {
            float r = sigm(arA[q] + arB[q] + bias_r);
            float z = sigm(azA[q] + azB[q] + bias_z);
            float n = tanh_f(xn[q] + bxn + r * (anA[q] + anB[q] + bhn));
            float hn = (1.0f - z) * n + z * hprev[q];
            hprev[q] = hn;
            hw[((l4 << 2) + q) * XSH + jj] = f2bf(hn);
        }
        gbar(ctr, myph, lane);
        cur ^= 1;
    };

    // ---- prologue: stage chunk 0 ----
    issue(0);
    commit(0);
    gbar(ctr, myph, lane);

    // ---- main: 31 full chunks of 8 steps (t = 0..247), per group, async ----
    for (int c = 0; c < 31; ++c) {
        issue((c + 1) * TCH);           // prefetch; gbar never drains vmcnt
        const int bx = c & 1;
        f32x4 xr[4], xz[4], xn[4];
        xg_phase(bx, 0, 4, xr, xz, xn);
#pragma unroll
        for (int tt = 0; tt < 4; ++tt) recur(xr[tt], xz[tt], xn[tt]);
        xg_phase(bx, 4, 4, xr, xz, xn);
#pragma unroll
        for (int tt = 0; tt < 4; ++tt) recur(xr[tt], xz[tt], xn[tt]);
        commit((c + 1) & 1);
        gbar(ctr, myph, lane);
    }
    // ---- tail chunk: 7 steps (t = 248..254), buffer 1 ----
    {
        f32x4 xr[4], xz[4], xn[4];
        xg_phase(1, 0, 4, xr, xz, xn);
#pragma unroll
        for (int tt = 0; tt < 4; ++tt) recur(xr[tt], xz[tt], xn[tt]);
        xg_phase(1, 4, 3, xr, xz, xn);
#pragma unroll
        for (int tt = 0; tt < 3; ++tt) recur(xr[tt], xz[tt], xn[tt]);
    }

    __syncthreads();   // both groups done; x/h regions now dead

    // ================= fused MLP epilogue (LDS-resident weights) =================
    float* wl = (float*)smem;   // sidx region (>= OFF_IDX) preserved

    for (int i = tid; i < 8192; i += NTHR) wl[OW1 + (i >> 7) * 129 + (i & 127)] = W1[i];
    for (int i = tid; i < 2048; i += NTHR) wl[OW2 + (i >> 6) * 65  + (i & 63)]  = W2[i];
    for (int i = tid; i < 512;  i += NTHR) wl[OW3 + (i >> 5) * 33  + (i & 31)]  = W3[i];
    for (int i = tid; i < 5120; i += NTHR) wl[OWL + (i / 80) * 81  + (i % 80)]  = Wl[i];
#pragma unroll
    for (int q = 0; q < 4; ++q)
        wl[OHF + (gid * GROWS + (l4 << 2) + q) * 128 + jj] = hprev[q];
    __syncthreads();

    // wave wv handles block rows 2*wv, 2*wv+1  (wv 0..15 -> rows 0..31)
    for (int mloc = 0; mloc < 2; ++mloc) {
        const int m = (wv << 1) + mloc;
        {
            float s = b1[lane];
            const float* w = wl + OW1 + lane * 129;
            for (int k = 0; k < 128; ++k) s += wl[OHF + m * 128 + k] * w[k];
            wl[OS1 + wv * 64 + lane] = leaky(s);
        }
        __syncthreads();
        if (lane < 32) {
            float s = b2[lane];
            const float* w = wl + OW2 + lane * 65;
            for (int k = 0; k < 64; ++k) s += wl[OS1 + wv * 64 + k] * w[k];
            wl[OS2 + wv * 32 + lane] = leaky(s);
        } else {
            int d = lane - 32;
            wl[OSL + wv * 64 + d]      = slist[((size_t)d        * CS_ + sidx[(m << 6) + d])      * S_ + (S_ - 1)];
            wl[OSL + wv * 64 + d + 32] = slist[((size_t)(d + 32) * CS_ + sidx[(m << 6) + d + 32]) * S_ + (S_ - 1)];
        }
        __syncthreads();
        if (lane < 16) {
            float s = b3[lane];
            const float* w = wl + OW3 + lane * 33;
            for (int k = 0; k < 32; ++k) s += wl[OS2 + wv * 32 + k] * w[k];
            wl[OS3 + wv * 16 + lane] = leaky(s);
        }
        __syncthreads();
        {
            float s = bl[lane];
            const float* w = wl + OWL + lane * 81;
#pragma unroll
            for (int i = 0; i < 16; ++i) s += wl[OS3 + wv * 16 + i] * w[i];
            for (int d = 0; d < 64; ++d) s += wl[OSL + wv * 64 + d] * w[16 + d];
            out[(size_t)(bblk + m) * DIMC + lane] = leaky(s);
        }
        __syncthreads();
    }
}

extern "C" void kernel_launch(void* const* d_in, const int* in_sizes, int n_in,
                              void* d_out, int out_size, void* d_ws, size_t ws_size,
                              hipStream_t stream) {
    (void)in_sizes; (void)n_in; (void)out_size; (void)d_ws; (void)ws_size;
    const float* x       = (const float*)d_in[0];
    const int*   snippet = (const int*)  d_in[1];
    const float* slist   = (const float*)d_in[2];
    const float* W_ih    = (const float*)d_in[3];
    const float* W_hh    = (const float*)d_in[4];
    const float* b_ih    = (const float*)d_in[5];
    const float* b_hh    = (const float*)d_in[6];
    const float* W1      = (const float*)d_in[7];
    const float* b1      = (const float*)d_in[8];
    const float* W2      = (const float*)d_in[9];
    const float* b2      = (const float*)d_in[10];
    const float* W3      = (const float*)d_in[11];
    const float* b3      = (const float*)d_in[12];
    const float* Wl      = (const float*)d_in[13];
    const float* bl      = (const float*)d_in[14];
    float* out = (float*)d_out;

    hipLaunchKernelGGL(gru_fused, dim3(NBLK), dim3(NTHR), 0, stream,
                       x, snippet, slist, W_ih, W_hh, b_ih, b_hh,
                       W1, b1, W2, b2, W3, b3, Wl, bl, out);
}

// Round 9
// 2202.787 us; speedup vs baseline: 1.0013x; 1.0009x over previous
//
#include <hip/hip_runtime.h>
#include <hip/hip_bf16.h>

// Problem constants
#define B_    1024
#define DIMC  64      // DIM
#define T_    255     // S-1 sequence steps
#define H_    128
#define CS_   500
#define S_    256

// ===================== Kernel A: async 2-group, 1024 thr =====================
#define GROWS 16              // batch rows per group
#define MROWS 32              // rows per block = 2 async groups
#define NBLK  (B_ / MROWS)    // 32 blocks
#define NTHR  1024            // 16 waves: waves 0-7 = group 0, 8-15 = group 1
#define TCH   8               // timesteps staged per chunk
#define XSX   132             // x LDS row stride (shorts)
#define XSH   136             // h LDS row stride (shorts)

// VGPR law (R2..R8): compiler targets 2 workgroups/CU by default; launch_bounds
// arg2 only RAISES the floor. amdgpu_waves_per_eu(4,4) forces 4 waves/EU -> 128 VGPR.

#define XBYTES  (2 * TCH * GROWS * XSX * 2)   // per-group x region: 67,584
#define HBYTES  (2 * GROWS * XSH * 2)         // per-group h region: 8,704
#define OFF_H   (2 * XBYTES)                  // 135,168
#define OFF_IDX (OFF_H + 2 * HBYTES)          // 152,576
#define OFF_CTR (OFF_IDX + 8192)              // 160,768
#define SMEMB   (OFF_CTR + 256)               // 161,024 <= 163,840

typedef __attribute__((ext_vector_type(8))) short bf16x8;
typedef __attribute__((ext_vector_type(4))) float f32x4;

__device__ __forceinline__ unsigned short f2bf(float f) {
    unsigned int u = __builtin_bit_cast(unsigned int, f);
    return (unsigned short)((u + 0x7FFFu + ((u >> 16) & 1u)) >> 16);
}
__device__ __forceinline__ float fast_rcp(float x) { return __builtin_amdgcn_rcpf(x); }
__device__ __forceinline__ float sigm(float x)   { float e = __expf(-x); return fast_rcp(1.0f + e); }
__device__ __forceinline__ float tanh_f(float x) { float e = __expf(2.0f * x); return 1.0f - 2.0f * fast_rcp(1.0f + e); }
__device__ __forceinline__ float leaky(float x)  { return x > 0.0f ? x : 0.01f * x; }
__device__ __forceinline__ int   imin(int a, int b) { return a < b ? a : b; }
// Barrier WITHOUT vmcnt drain: keeps prefetch global loads in flight.
__device__ __forceinline__ void bar_lgkm() {
    asm volatile("s_waitcnt lgkmcnt(0)\n\ts_barrier" ::: "memory");
}
// Group-local spin barrier: monotone counter, 8 waves per group.
__device__ __forceinline__ void gbar(int* ctr, int& myph, int lane) {
    asm volatile("s_waitcnt lgkmcnt(0)" ::: "memory");
    myph += 8;
    if (lane == 0)
        __hip_atomic_fetch_add(ctr, 1, __ATOMIC_RELAXED, __HIP_MEMORY_SCOPE_WORKGROUP);
    while (__hip_atomic_load(ctr, __ATOMIC_RELAXED, __HIP_MEMORY_SCOPE_WORKGROUP) < myph)
        __builtin_amdgcn_s_sleep(1);
    asm volatile("" ::: "memory");
}

// Kernel A epilogue LDS layout (dword offsets)
#define OW1 0
#define OW2 8256
#define OW3 10336
#define OWL 10864
#define OHF 16048    // h fp32, 32 x 128
#define OS1 20144
#define OS2 21168
#define OS3 21680
#define OSL 21936

__global__ __launch_bounds__(NTHR) __attribute__((amdgpu_waves_per_eu(4, 4)))
void gru_async(const float* __restrict__ x, const int* __restrict__ snippet,
               const float* __restrict__ slist,
               const float* __restrict__ W_ih, const float* __restrict__ W_hh,
               const float* __restrict__ b_ih, const float* __restrict__ b_hh,
               const float* __restrict__ W1, const float* __restrict__ b1,
               const float* __restrict__ W2, const float* __restrict__ b2,
               const float* __restrict__ W3, const float* __restrict__ b3,
               const float* __restrict__ Wl, const float* __restrict__ bl,
               float* __restrict__ out)
{
    __shared__ __attribute__((aligned(16))) unsigned char smem[SMEMB];
    int* sidx = (int*)(smem + OFF_IDX);                      // [32*64]

    const int tid   = threadIdx.x;
    const int bblk  = blockIdx.x * MROWS;
    const int lane  = tid & 63;
    const int wv    = tid >> 6;          // 0..15
    const int gid   = wv >> 3;           // group 0/1
    const int wv8   = wv & 7;            // wave within group
    const int utid  = tid & 511;         // thread within group
    const int l15   = lane & 15;
    const int l4    = lane >> 4;
    const int bbase = bblk + gid * GROWS;

    unsigned short* shx_g = (unsigned short*)(smem + gid * XBYTES);
    unsigned short* shh_g = (unsigned short*)(smem + OFF_H + gid * HBYTES);
    int* sidx_g = sidx + gid * GROWS * DIMC;
    int* ctr    = (int*)(smem + OFF_CTR) + gid * 32;

    for (int i = tid; i < MROWS * DIMC; i += NTHR)
        sidx[i] = snippet[bblk * DIMC + i];
    for (int i = tid; i < 2 * 2 * GROWS * XSH; i += NTHR)
        ((unsigned short*)(smem + OFF_H))[i] = 0;
    if (tid < 2) *((int*)(smem + OFF_CTR) + tid * 32) = 0;

    bf16x8 wih[3][4], whh[3][4];
    {
        const int g = (wv8 << 4) + l15;
#pragma unroll
        for (int gt = 0; gt < 3; ++gt) {
#pragma unroll
            for (int kb = 0; kb < 4; ++kb) {
                const float* p1 = W_ih + (size_t)(gt * 128 + g) * 128 + kb * 32 + (l4 << 3);
                const float* p2 = W_hh + (size_t)(gt * 128 + g) * 128 + kb * 32 + (l4 << 3);
                f32x4 a0, a1, c0, c1;
                __builtin_memcpy(&a0, p1, 16); __builtin_memcpy(&a1, p1 + 4, 16);
                __builtin_memcpy(&c0, p2, 16); __builtin_memcpy(&c1, p2 + 4, 16);
                bf16x8 a, c;
#pragma unroll
                for (int e = 0; e < 4; ++e) {
                    a[e] = (short)f2bf(a0[e]); a[e + 4] = (short)f2bf(a1[e]);
                    c[e] = (short)f2bf(c0[e]); c[e + 4] = (short)f2bf(c1[e]);
                }
                wih[gt][kb] = a; whh[gt][kb] = c;
            }
        }
    }
    const int jj = (wv8 << 4) + l15;
    const float bias_r = b_ih[jj]       + b_hh[jj];
    const float bias_z = b_ih[128 + jj] + b_hh[128 + jj];
    const float bxn    = b_ih[256 + jj];
    const float bhn    = b_hh[256 + jj];

    __syncthreads();

    int rowu[2], k0u[2], isx[2];
    const float* pa[2]; const float* pb[2];
#pragma unroll
    for (int un = 0; un < 2; ++un) {
        int u  = utid + un * 512;
        int r  = u >> 6;
        int k0 = (u & 63) << 1;
        rowu[un] = r; k0u[un] = k0;
        if (k0 < DIMC) {
            isx[un] = 1;
            pa[un] = x + ((size_t)(bbase + r) * DIMC + k0) * T_;
            pb[un] = pa[un] + T_;
        } else {
            isx[un] = 0;
            int d = k0 - DIMC;
            pa[un] = slist + ((size_t)d       * CS_ + sidx_g[(r << 6) + d])     * S_;
            pb[un] = slist + ((size_t)(d + 1) * CS_ + sidx_g[(r << 6) + d + 1]) * S_;
        }
    }

    f32x4 sa[2][2], sb[2][2];

    auto issue = [&](int t0) {
#pragma unroll
        for (int un = 0; un < 2; ++un) {
            if (isx[un] && t0 + TCH - 1 > T_ - 1) {
#pragma unroll
                for (int g = 0; g < 2; ++g) {
                    f32x4 va, vb;
#pragma unroll
                    for (int e = 0; e < 4; ++e) {
                        int tt = imin(t0 + g * 4 + e, T_ - 1);
                        va[e] = pa[un][tt]; vb[e] = pb[un][tt];
                    }
                    sa[un][g] = va; sb[un][g] = vb;
                }
            } else {
#pragma unroll
                for (int g = 0; g < 2; ++g) {
                    f32x4 va, vb;
                    __builtin_memcpy(&va, pa[un] + t0 + g * 4, 16);
                    __builtin_memcpy(&vb, pb[un] + t0 + g * 4, 16);
                    sa[un][g] = va; sb[un][g] = vb;
                }
            }
        }
    };

    auto commit = [&](int buf) {
        unsigned short* dst = shx_g + buf * (TCH * GROWS * XSX);
#pragma unroll
        for (int un = 0; un < 2; ++un) {
#pragma unroll
            for (int g = 0; g < 2; ++g) {
#pragma unroll
                for (int e = 0; e < 4; ++e) {
                    int t = g * 4 + e;
                    unsigned pk = (unsigned)f2bf(sa[un][g][e]) | ((unsigned)f2bf(sb[un][g][e]) << 16);
                    *(unsigned*)&dst[(t * GROWS + rowu[un]) * XSX + k0u[un]] = pk;
                }
            }
        }
    };

    int cur = 0;
    int myph = 0;
    float hprev[4] = {0.f, 0.f, 0.f, 0.f};
    const f32x4 Z = {0.f, 0.f, 0.f, 0.f};

    auto xg_phase = [&](int buf, int tb, int nt, f32x4* xr, f32x4* xz, f32x4* xn) {
        const unsigned short* base = shx_g + buf * (TCH * GROWS * XSX);
#pragma unroll
        for (int tt = 0; tt < 4; ++tt) {
            if (tt >= nt) break;
            const unsigned short* xp = base + ((tb + tt) * GROWS + l15) * XSX + (l4 << 3);
            bf16x8 a[4];
#pragma unroll
            for (int kb = 0; kb < 4; ++kb) a[kb] = *(const bf16x8*)(xp + kb * 32);
            f32x4 r = Z, z = Z, n = Z;
#pragma unroll
            for (int kb = 0; kb < 4; ++kb) {
                r = __builtin_amdgcn_mfma_f32_16x16x32_bf16(a[kb], wih[0][kb], r, 0, 0, 0);
                z = __builtin_amdgcn_mfma_f32_16x16x32_bf16(a[kb], wih[1][kb], z, 0, 0, 0);
                n = __builtin_amdgcn_mfma_f32_16x16x32_bf16(a[kb], wih[2][kb], n, 0, 0, 0);
            }
            xr[tt] = r; xz[tt] = z; xn[tt] = n;
        }
    };

    auto recur = [&](f32x4 xr, f32x4 xz, f32x4 xn) {
        const unsigned short* hp = shh_g + cur * (GROWS * XSH) + l15 * XSH + (l4 << 3);
        bf16x8 h0 = *(const bf16x8*)(hp);
        bf16x8 h1 = *(const bf16x8*)(hp + 32);
        bf16x8 h2 = *(const bf16x8*)(hp + 64);
        bf16x8 h3 = *(const bf16x8*)(hp + 96);
        f32x4 arA = __builtin_amdgcn_mfma_f32_16x16x32_bf16(h0, whh[0][0], xr, 0, 0, 0);
        f32x4 azA = __builtin_amdgcn_mfma_f32_16x16x32_bf16(h0, whh[1][0], xz, 0, 0, 0);
        f32x4 anA = __builtin_amdgcn_mfma_f32_16x16x32_bf16(h0, whh[2][0], Z,  0, 0, 0);
        f32x4 arB = __builtin_amdgcn_mfma_f32_16x16x32_bf16(h2, whh[0][2], Z,  0, 0, 0);
        f32x4 azB = __builtin_amdgcn_mfma_f32_16x16x32_bf16(h2, whh[1][2], Z,  0, 0, 0);
        f32x4 anB = __builtin_amdgcn_mfma_f32_16x16x32_bf16(h2, whh[2][2], Z,  0, 0, 0);
        arA = __builtin_amdgcn_mfma_f32_16x16x32_bf16(h1, whh[0][1], arA, 0, 0, 0);
        azA = __builtin_amdgcn_mfma_f32_16x16x32_bf16(h1, whh[1][1], azA, 0, 0, 0);
        anA = __builtin_amdgcn_mfma_f32_16x16x32_bf16(h1, whh[2][1], anA, 0, 0, 0);
        arB = __builtin_amdgcn_mfma_f32_16x16x32_bf16(h3, whh[0][3], arB, 0, 0, 0);
        azB = __builtin_amdgcn_mfma_f32_16x16x32_bf16(h3, whh[1][3], azB, 0, 0, 0);
        anB = __builtin_amdgcn_mfma_f32_16x16x32_bf16(h3, whh[2][3], anB, 0, 0, 0);
        unsigned short* hw = shh_g + (cur ^ 1) * (GROWS * XSH);
#pragma unroll
        for (int q = 0; q < 4; ++q) {
            float r = sigm(arA[q] + arB[q] + bias_r);
            float z = sigm(azA[q] + azB[q] + bias_z);
            float n = tanh_f(xn[q] + bxn + r * (anA[q] + anB[q] + bhn));
            float hn = (1.0f - z) * n + z * hprev[q];
            hprev[q] = hn;
            hw[((l4 << 2) + q) * XSH + jj] = f2bf(hn);
        }
        gbar(ctr, myph, lane);
        cur ^= 1;
    };

    issue(0);
    commit(0);
    gbar(ctr, myph, lane);

    for (int c = 0; c < 31; ++c) {
        issue((c + 1) * TCH);
        const int bx = c & 1;
        f32x4 xr[4], xz[4], xn[4];
        xg_phase(bx, 0, 4, xr, xz, xn);
#pragma unroll
        for (int tt = 0; tt < 4; ++tt) recur(xr[tt], xz[tt], xn[tt]);
        xg_phase(bx, 4, 4, xr, xz, xn);
#pragma unroll
        for (int tt = 0; tt < 4; ++tt) recur(xr[tt], xz[tt], xn[tt]);
        commit((c + 1) & 1);
        gbar(ctr, myph, lane);
    }
    {
        f32x4 xr[4], xz[4], xn[4];
        xg_phase(1, 0, 4, xr, xz, xn);
#pragma unroll
        for (int tt = 0; tt < 4; ++tt) recur(xr[tt], xz[tt], xn[tt]);
        xg_phase(1, 4, 3, xr, xz, xn);
#pragma unroll
        for (int tt = 0; tt < 3; ++tt) recur(xr[tt], xz[tt], xn[tt]);
    }

    __syncthreads();

    float* wl = (float*)smem;
    for (int i = tid; i < 8192; i += NTHR) wl[OW1 + (i >> 7) * 129 + (i & 127)] = W1[i];
    for (int i = tid; i < 2048; i += NTHR) wl[OW2 + (i >> 6) * 65  + (i & 63)]  = W2[i];
    for (int i = tid; i < 512;  i += NTHR) wl[OW3 + (i >> 5) * 33  + (i & 31)]  = W3[i];
    for (int i = tid; i < 5120; i += NTHR) wl[OWL + (i / 80) * 81  + (i % 80)]  = Wl[i];
#pragma unroll
    for (int q = 0; q < 4; ++q)
        wl[OHF + (gid * GROWS + (l4 << 2) + q) * 128 + jj] = hprev[q];
    __syncthreads();

    for (int mloc = 0; mloc < 2; ++mloc) {
        const int m = (wv << 1) + mloc;
        {
            float s = b1[lane];
            const float* w = wl + OW1 + lane * 129;
            for (int k = 0; k < 128; ++k) s += wl[OHF + m * 128 + k] * w[k];
            wl[OS1 + wv * 64 + lane] = leaky(s);
        }
        __syncthreads();
        if (lane < 32) {
            float s = b2[lane];
            const float* w = wl + OW2 + lane * 65;
            for (int k = 0; k < 64; ++k) s += wl[OS1 + wv * 64 + k] * w[k];
            wl[OS2 + wv * 32 + lane] = leaky(s);
        } else {
            int d = lane - 32;
            wl[OSL + wv * 64 + d]      = slist[((size_t)d        * CS_ + sidx[(m << 6) + d])      * S_ + (S_ - 1)];
            wl[OSL + wv * 64 + d + 32] = slist[((size_t)(d + 32) * CS_ + sidx[(m << 6) + d + 32]) * S_ + (S_ - 1)];
        }
        __syncthreads();
        if (lane < 16) {
            float s = b3[lane];
            const float* w = wl + OW3 + lane * 33;
            for (int k = 0; k < 32; ++k) s += wl[OS2 + wv * 32 + k] * w[k];
            wl[OS3 + wv * 16 + lane] = leaky(s);
        }
        __syncthreads();
        {
            float s = bl[lane];
            const float* w = wl + OWL + lane * 81;
#pragma unroll
            for (int i = 0; i < 16; ++i) s += wl[OS3 + wv * 16 + i] * w[i];
            for (int d = 0; d < 64; ++d) s += wl[OSL + wv * 64 + d] * w[16 + d];
            out[(size_t)(bblk + m) * DIMC + lane] = leaky(s);
        }
        __syncthreads();
    }
}

// ===================== Kernel B: fallback = proven R3 (512 thr) =====================
#define FB_XSTR   136
#define FB_OFF_H  69632
#define FB_OFF_IDX 78336
#define FB_SMEMB  82432
#define FB_OW1 0
#define FB_OW2 8256
#define FB_OW3 10336
#define FB_OWL 10864
#define FB_OHF 16048
#define FB_OS1 18096
#define FB_OS2 18608
#define FB_OS3 18864
#define FB_OSL 18992

__global__ __launch_bounds__(512, 2)
void gru_fb(const float* __restrict__ x, const int* __restrict__ snippet,
            const float* __restrict__ slist,
            const float* __restrict__ W_ih, const float* __restrict__ W_hh,
            const float* __restrict__ b_ih, const float* __restrict__ b_hh,
            const float* __restrict__ W1, const float* __restrict__ b1,
            const float* __restrict__ W2, const float* __restrict__ b2,
            const float* __restrict__ W3, const float* __restrict__ b3,
            const float* __restrict__ Wl, const float* __restrict__ bl,
            float* __restrict__ out)
{
    __shared__ __attribute__((aligned(16))) unsigned char smem[FB_SMEMB];
    unsigned short* shx0 = (unsigned short*)smem;
    unsigned short* shh0 = (unsigned short*)(smem + FB_OFF_H);
    int*            sidx = (int*)(smem + FB_OFF_IDX);

    const int tid   = threadIdx.x;
    const int bbase = blockIdx.x * 16;
    const int lane  = tid & 63;
    const int wv    = tid >> 6;
    const int l15   = lane & 15;
    const int l4    = lane >> 4;

    for (int i = tid; i < 16 * DIMC; i += 512) {
        int r = i >> 6, d = i & 63;
        sidx[i] = snippet[(bbase + r) * DIMC + d];
    }
    for (int i = tid; i < 16 * FB_XSTR; i += 512) shh0[i] = 0;

    bf16x8 wih[3][4], whh[3][4];
    {
        const int g = (wv << 4) + l15;
#pragma unroll
        for (int gt = 0; gt < 3; ++gt) {
#pragma unroll
            for (int kb = 0; kb < 4; ++kb) {
                const float* p1 = W_ih + (size_t)(gt * 128 + g) * 128 + kb * 32 + (l4 << 3);
                const float* p2 = W_hh + (size_t)(gt * 128 + g) * 128 + kb * 32 + (l4 << 3);
                f32x4 a0, a1, c0, c1;
                __builtin_memcpy(&a0, p1, 16); __builtin_memcpy(&a1, p1 + 4, 16);
                __builtin_memcpy(&c0, p2, 16); __builtin_memcpy(&c1, p2 + 4, 16);
                bf16x8 a, c;
#pragma unroll
                for (int e = 0; e < 4; ++e) {
                    a[e] = (short)f2bf(a0[e]); a[e + 4] = (short)f2bf(a1[e]);
                    c[e] = (short)f2bf(c0[e]); c[e + 4] = (short)f2bf(c1[e]);
                }
                wih[gt][kb] = a; whh[gt][kb] = c;
            }
        }
    }
    const int jj = (wv << 4) + l15;
    const float bias_r = b_ih[jj]       + b_hh[jj];
    const float bias_z = b_ih[128 + jj] + b_hh[128 + jj];
    const float bxn    = b_ih[256 + jj];
    const float bhn    = b_hh[256 + jj];

    __syncthreads();

    int rowu[2], k0u[2], isx[2];
    const float* pa[2]; const float* pb[2];
#pragma unroll
    for (int un = 0; un < 2; ++un) {
        int u  = tid + un * 512;
        int r  = u >> 6;
        int k0 = (u & 63) << 1;
        rowu[un] = r; k0u[un] = k0;
        if (k0 < DIMC) {
            isx[un] = 1;
            pa[un] = x + ((size_t)(bbase + r) * DIMC + k0) * T_;
            pb[un] = pa[un] + T_;
        } else {
            isx[un] = 0;
            int d = k0 - DIMC;
            pa[un] = slist + ((size_t)d       * CS_ + sidx[(r << 6) + d])     * S_;
            pb[un] = slist + ((size_t)(d + 1) * CS_ + sidx[(r << 6) + d + 1]) * S_;
        }
    }

    f32x4 sa[2][2], sb[2][2];

    auto issue = [&](int t0) {
#pragma unroll
        for (int un = 0; un < 2; ++un) {
            if (isx[un] && t0 + 8 - 1 > T_ - 1) {
#pragma unroll
                for (int g = 0; g < 2; ++g) {
                    f32x4 va, vb;
#pragma unroll
                    for (int e = 0; e < 4; ++e) {
                        int tt = imin(t0 + g * 4 + e, T_ - 1);
                        va[e] = pa[un][tt]; vb[e] = pb[un][tt];
                    }
                    sa[un][g] = va; sb[un][g] = vb;
                }
            } else {
#pragma unroll
                for (int g = 0; g < 2; ++g) {
                    f32x4 va, vb;
                    __builtin_memcpy(&va, pa[un] + t0 + g * 4, 16);
                    __builtin_memcpy(&vb, pb[un] + t0 + g * 4, 16);
                    sa[un][g] = va; sb[un][g] = vb;
                }
            }
        }
    };

    auto commit = [&](int buf) {
        unsigned short* dst = shx0 + buf * (8 * 16 * FB_XSTR);
#pragma unroll
        for (int un = 0; un < 2; ++un) {
#pragma unroll
            for (int g = 0; g < 2; ++g) {
#pragma unroll
                for (int e = 0; e < 4; ++e) {
                    int t = g * 4 + e;
                    unsigned pk = (unsigned)f2bf(sa[un][g][e]) | ((unsigned)f2bf(sb[un][g][e]) << 16);
                    *(unsigned*)&dst[(t * 16 + rowu[un]) * FB_XSTR + k0u[un]] = pk;
                }
            }
        }
    };

    int cur = 0;
    float hprev[4] = {0.f, 0.f, 0.f, 0.f};
    const f32x4 Z = {0.f, 0.f, 0.f, 0.f};

    auto xg_phase = [&](int buf, int tb, int nt, f32x4* xr, f32x4* xz, f32x4* xn) {
        const unsigned short* base = shx0 + buf * (8 * 16 * FB_XSTR);
#pragma unroll
        for (int tt = 0; tt < 4; ++tt) {
            if (tt >= nt) break;
            const unsigned short* xp = base + ((tb + tt) * 16 + l15) * FB_XSTR + (l4 << 3);
            bf16x8 a[4];
#pragma unroll
            for (int kb = 0; kb < 4; ++kb) a[kb] = *(const bf16x8*)(xp + kb * 32);
            f32x4 r = Z, z = Z, n = Z;
#pragma unroll
            for (int kb = 0; kb < 4; ++kb) {
                r = __builtin_amdgcn_mfma_f32_16x16x32_bf16(a[kb], wih[0][kb], r, 0, 0, 0);
                z = __builtin_amdgcn_mfma_f32_16x16x32_bf16(a[kb], wih[1][kb], z, 0, 0, 0);
                n = __builtin_amdgcn_mfma_f32_16x16x32_bf16(a[kb], wih[2][kb], n, 0, 0, 0);
            }
            xr[tt] = r; xz[tt] = z; xn[tt] = n;
        }
    };

    auto recur = [&](f32x4 xr, f32x4 xz, f32x4 xn) {
        const unsigned short* hp = shh0 + cur * (16 * FB_XSTR) + l15 * FB_XSTR + (l4 << 3);
        bf16x8 h0 = *(const bf16x8*)(hp);
        bf16x8 h1 = *(const bf16x8*)(hp + 32);
        bf16x8 h2 = *(const bf16x8*)(hp + 64);
        bf16x8 h3 = *(const bf16x8*)(hp + 96);
        f32x4 arA = __builtin_amdgcn_mfma_f32_16x16x32_bf16(h0, whh[0][0], xr, 0, 0, 0);
        f32x4 azA = __builtin_amdgcn_mfma_f32_16x16x32_bf16(h0, whh[1][0], xz, 0, 0, 0);
        f32x4 anA = __builtin_amdgcn_mfma_f32_16x16x32_bf16(h0, whh[2][0], Z,  0, 0, 0);
        f32x4 arB = __builtin_amdgcn_mfma_f32_16x16x32_bf16(h2, whh[0][2], Z,  0, 0, 0);
        f32x4 azB = __builtin_amdgcn_mfma_f32_16x16x32_bf16(h2, whh[1][2], Z,  0, 0, 0);
        f32x4 anB = __builtin_amdgcn_mfma_f32_16x16x32_bf16(h2, whh[2][2], Z,  0, 0, 0);
        arA = __builtin_amdgcn_mfma_f32_16x16x32_bf16(h1, whh[0][1], arA, 0, 0, 0);
        azA = __builtin_amdgcn_mfma_f32_16x16x32_bf16(h1, whh[1][1], azA, 0, 0, 0);
        anA = __builtin_amdgcn_mfma_f32_16x16x32_bf16(h1, whh[2][1], anA, 0, 0, 0);
        arB = __builtin_amdgcn_mfma_f32_16x16x32_bf16(h3, whh[0][3], arB, 0, 0, 0);
        azB = __builtin_amdgcn_mfma_f32_16x16x32_bf16(h3, whh[1][3], azB, 0, 0, 0);
        anB = __builtin_amdgcn_mfma_f32_16x16x32_bf16(h3, whh[2][3], anB, 0, 0, 0);
        unsigned short* hw = shh0 + (cur ^ 1) * (16 * FB_XSTR);
#pragma unroll
        for (int q = 0; q < 4; ++q) {
            float r = sigm(arA[q] + arB[q] + bias_r);
            float z = sigm(azA[q] + azB[q] + bias_z);
            float n = tanh_f(xn[q] + bxn + r * (anA[q] + anB[q] + bhn));
            float hn = (1.0f - z) * n + z * hprev[q];
            hprev[q] = hn;
            hw[((l4 << 2) + q) * FB_XSTR + jj] = f2bf(hn);
        }
        bar_lgkm();
        cur ^= 1;
    };

    issue(0);
    commit(0);
    __syncthreads();

    for (int c = 0; c < 31; ++c) {
        issue((c + 1) * 8);
        const int bx = c & 1;
        f32x4 xr[4], xz[4], xn[4];
        xg_phase(bx, 0, 4, xr, xz, xn);
#pragma unroll
        for (int tt = 0; tt < 4; ++tt) recur(xr[tt], xz[tt], xn[tt]);
        xg_phase(bx, 4, 4, xr, xz, xn);
#pragma unroll
        for (int tt = 0; tt < 4; ++tt) recur(xr[tt], xz[tt], xn[tt]);
        commit((c + 1) & 1);
        bar_lgkm();
    }
    {
        f32x4 xr[4], xz[4], xn[4];
        xg_phase(1, 0, 4, xr, xz, xn);
#pragma unroll
        for (int tt = 0; tt < 4; ++tt) recur(xr[tt], xz[tt], xn[tt]);
        xg_phase(1, 4, 3, xr, xz, xn);
#pragma unroll
        for (int tt = 0; tt < 3; ++tt) recur(xr[tt], xz[tt], xn[tt]);
    }

    float* wl = (float*)smem;
    for (int i = tid; i < 8192; i += 512) wl[FB_OW1 + (i >> 7) * 129 + (i & 127)] = W1[i];
    for (int i = tid; i < 2048; i += 512) wl[FB_OW2 + (i >> 6) * 65  + (i & 63)]  = W2[i];
    for (int i = tid; i < 512;  i += 512) wl[FB_OW3 + (i >> 5) * 33  + (i & 31)]  = W3[i];
    for (int i = tid; i < 5120; i += 512) wl[FB_OWL + (i / 80) * 81  + (i % 80)]  = Wl[i];
#pragma unroll
    for (int q = 0; q < 4; ++q) wl[FB_OHF + ((l4 << 2) + q) * 128 + jj] = hprev[q];
    __syncthreads();

    for (int mloc = 0; mloc < 2; ++mloc) {
        const int m = (wv << 1) + mloc;
        {
            float s = b1[lane];
            const float* w = wl + FB_OW1 + lane * 129;
            for (int k = 0; k < 128; ++k) s += wl[FB_OHF + m * 128 + k] * w[k];
            wl[FB_OS1 + wv * 64 + lane] = leaky(s);
        }
        __syncthreads();
        if (lane < 32) {
            float s = b2[lane];
            const float* w = wl + FB_OW2 + lane * 65;
            for (int k = 0; k < 64; ++k) s += wl[FB_OS1 + wv * 64 + k] * w[k];
            wl[FB_OS2 + wv * 32 + lane] = leaky(s);
        } else {
            int d = lane - 32;
            wl[FB_OSL + wv * 64 + d]      = slist[((size_t)d        * CS_ + sidx[(m << 6) + d])      * S_ + (S_ - 1)];
            wl[FB_OSL + wv * 64 + d + 32] = slist[((size_t)(d + 32) * CS_ + sidx[(m << 6) + d + 32]) * S_ + (S_ - 1)];
        }
        __syncthreads();
        if (lane < 16) {
            float s = b3[lane];
            const float* w = wl + FB_OW3 + lane * 33;
            for (int k = 0; k < 32; ++k) s += wl[FB_OS2 + wv * 32 + k] * w[k];
            wl[FB_OS3 + wv * 16 + lane] = leaky(s);
        }
        __syncthreads();
        {
            float s = bl[lane];
            const float* w = wl + FB_OWL + lane * 81;
#pragma unroll
            for (int i = 0; i < 16; ++i) s += wl[FB_OS3 + wv * 16 + i] * w[i];
            for (int d = 0; d < 64; ++d) s += wl[FB_OSL + wv * 64 + d] * w[16 + d];
            out[(size_t)(bbase + m) * DIMC + lane] = leaky(s);
        }
        __syncthreads();
    }
}

extern "C" void kernel_launch(void* const* d_in, const int* in_sizes, int n_in,
                              void* d_out, int out_size, void* d_ws, size_t ws_size,
                              hipStream_t stream) {
    (void)in_sizes; (void)n_in; (void)out_size; (void)d_ws; (void)ws_size;
    const float* x       = (const float*)d_in[0];
    const int*   snippet = (const int*)  d_in[1];
    const float* slist   = (const float*)d_in[2];
    const float* W_ih    = (const float*)d_in[3];
    const float* W_hh    = (const float*)d_in[4];
    const float* b_ih    = (const float*)d_in[5];
    const float* b_hh    = (const float*)d_in[6];
    const float* W1      = (const float*)d_in[7];
    const float* b1      = (const float*)d_in[8];
    const float* W2      = (const float*)d_in[9];
    const float* b2      = (const float*)d_in[10];
    const float* W3      = (const float*)d_in[11];
    const float* b3      = (const float*)d_in[12];
    const float* Wl      = (const float*)d_in[13];
    const float* bl      = (const float*)d_in[14];
    float* out = (float*)d_out;

    // Runtime dispatch: only use the async kernel if the VGPR cap was actually
    // lifted (>=100 regs means amdgpu_waves_per_eu(4,4) took effect; 64 means
    // the compiler spilled -> use proven fallback). Deterministic every call.
    hipFuncAttributes fa{};
    bool useAsync = false;
    if (hipFuncGetAttributes(&fa, reinterpret_cast<const void*>(gru_async)) == hipSuccess)
        useAsync = (fa.numRegs >= 100);

    if (useAsync) {
        hipLaunchKernelGGL(gru_async, dim3(NBLK), dim3(NTHR), 0, stream,
                           x, snippet, slist, W_ih, W_hh, b_ih, b_hh,
                           W1, b1, W2, b2, W3, b3, Wl, bl, out);
    } else {
        hipLaunchKernelGGL(gru_fb, dim3(64), dim3(512), 0, stream,
                           x, snippet, slist, W_ih, W_hh, b_ih, b_hh,
                           W1, b1, W2, b2, W3, b3, Wl, bl, out);
    }
}

// Round 10
// 337.468 us; speedup vs baseline: 6.5358x; 6.5274x over previous
//
#include <hip/hip_runtime.h>
#include <hip/hip_bf16.h>

// Problem constants
#define B_    1024
#define DIMC  64      // DIM
#define T_    255     // S-1 sequence steps
#define H_    128
#define CS_   500
#define S_    256

#define MROWS 16             // batch rows per block
#define NBLK  (B_ / MROWS)   // 64 blocks
#define NTHR  512            // 8 waves; wave owns 16 gate-cols (as 4 consecutive per lane-quad)
#define TCH   8              // timesteps staged per chunk
#define XSX   152            // x LDS row stride (shorts): 304B rows, 16B aligned, ~2-way banks
#define XSH   152            // h LDS row stride (shorts)
#define HSZ   (MROWS * XSH)

// LDS carve (bytes): x 2x38912=77824 | h 2x4864=9728 @77824 | idx @87552 | total 91648
#define OFF_H   77824
#define OFF_IDX 87552
#define SMEMB   91648

typedef __attribute__((ext_vector_type(8))) short bf16x8;
typedef __attribute__((ext_vector_type(4))) float f32x4;

#define LOG2E 1.4426950408889634f

__device__ __forceinline__ unsigned short f2bf(float f) {
    unsigned int u = __builtin_bit_cast(unsigned int, f);
    return (unsigned short)((u + 0x7FFFu + ((u >> 16) & 1u)) >> 16);
}
__device__ __forceinline__ float fast_rcp(float x) { return __builtin_amdgcn_rcpf(x); }
#if __has_builtin(__builtin_amdgcn_exp2f)
__device__ __forceinline__ float EXP2(float x) { return __builtin_amdgcn_exp2f(x); }
#else
__device__ __forceinline__ float EXP2(float x) { float r; asm("v_exp_f32 %0, %1" : "=v"(r) : "v"(x)); return r; }
#endif
__device__ __forceinline__ unsigned cvt_pk_bf16(float lo, float hi) {
    unsigned r; asm("v_cvt_pk_bf16_f32 %0, %1, %2" : "=v"(r) : "v"(lo), "v"(hi)); return r;
}
__device__ __forceinline__ float leaky(float x)  { return x > 0.0f ? x : 0.01f * x; }
__device__ __forceinline__ int   imin(int a, int b) { return a < b ? a : b; }
// Barrier WITHOUT vmcnt drain: keeps prefetch global loads in flight.
__device__ __forceinline__ void bar_lgkm() {
    asm volatile("s_waitcnt lgkmcnt(0)\n\ts_barrier" ::: "memory");
}

// Epilogue LDS layout (dword offsets; all < OFF_IDX/4)
#define OW1 0        // W1 padded 64 x 129
#define OW2 8256     // W2 padded 32 x 65
#define OW3 10336    // W3 padded 16 x 33
#define OWL 10864    // W_last padded 64 x 81
#define OHF 16048    // h fp32, 16 x 128
#define OS1 18096    // s1 per wave 8 x 64
#define OS2 18608    // s2 per wave 8 x 32
#define OS3 18864    // s3 per wave 8 x 16
#define OSL 18992    // last per wave 8 x 64   (ends 19504 dw = 78016 B < OFF_IDX)

__global__ __launch_bounds__(NTHR, 2)
void gru_fused(const float* __restrict__ x, const int* __restrict__ snippet,
               const float* __restrict__ slist,
               const float* __restrict__ W_ih, const float* __restrict__ W_hh,
               const float* __restrict__ b_ih, const float* __restrict__ b_hh,
               const float* __restrict__ W1, const float* __restrict__ b1,
               const float* __restrict__ W2, const float* __restrict__ b2,
               const float* __restrict__ W3, const float* __restrict__ b3,
               const float* __restrict__ Wl, const float* __restrict__ bl,
               float* __restrict__ out)
{
    __shared__ __attribute__((aligned(16))) unsigned char smem[SMEMB];
    unsigned short* shx = (unsigned short*)smem;               // [2][TCH][16][XSX]
    unsigned short* shh = (unsigned short*)(smem + OFF_H);     // [2][16][XSH]
    int*            sidx = (int*)(smem + OFF_IDX);             // [16*64]

    const int tid   = threadIdx.x;
    const int bbase = blockIdx.x * MROWS;
    const int lane  = tid & 63;
    const int wv    = tid >> 6;          // 0..7
    const int l15   = lane & 15;         // batch row (as B-frag/D-col index)
    const int l4    = lane >> 4;         // k-chunk / gate-col quad

    // ---- snippet indices, zero h bufs ----
    for (int i = tid; i < MROWS * DIMC; i += NTHR) {
        int r = i >> 6, d = i & 63;
        sidx[i] = snippet[(bbase + r) * DIMC + d];
    }
    for (int i = tid; i < 2 * HSZ; i += NTHR) shh[i] = 0;

    // ---- weight A-fragments in registers, PRE-SCALED for exp2-direct gates ----
    // gate 0 (r), 1 (z): scale -log2e ; gate 2 (n): scale +2*log2e
    // A-frag layout: lane&15 = gate-col (within wave's 16), lane>>4 * 8 + e = k
    bf16x8 wih[3][4], whh[3][4];   // 96 VGPR
    {
        const int g = (wv << 4) + l15;   // gate-col within gate block
        const float sc[3] = { -LOG2E, -LOG2E, 2.0f * LOG2E };
#pragma unroll
        for (int gt = 0; gt < 3; ++gt) {
#pragma unroll
            for (int kb = 0; kb < 4; ++kb) {
                const float* p1 = W_ih + (size_t)(gt * 128 + g) * 128 + kb * 32 + (l4 << 3);
                const float* p2 = W_hh + (size_t)(gt * 128 + g) * 128 + kb * 32 + (l4 << 3);
                f32x4 a0, a1, c0, c1;
                __builtin_memcpy(&a0, p1, 16); __builtin_memcpy(&a1, p1 + 4, 16);
                __builtin_memcpy(&c0, p2, 16); __builtin_memcpy(&c1, p2 + 4, 16);
                bf16x8 a, c;
#pragma unroll
                for (int e = 0; e < 4; ++e) {
                    a[e] = (short)f2bf(a0[e] * sc[gt]); a[e + 4] = (short)f2bf(a1[e] * sc[gt]);
                    c[e] = (short)f2bf(c0[e] * sc[gt]); c[e + 4] = (short)f2bf(c1[e] * sc[gt]);
                }
                wih[gt][kb] = a; whh[gt][kb] = c;
            }
        }
    }
    // per-lane bias seeds: lane's gate-cols = wv*16 + l4*4 + q  (D-row = l4*4+q)
    const int c0col = (wv << 4) + (l4 << 2);
    f32x4 biasR4, biasZ4, biasXN4, biasHN4;
#pragma unroll
    for (int q = 0; q < 4; ++q) {
        int col = c0col + q;
        biasR4[q]  = (b_ih[col]       + b_hh[col])       * (-LOG2E);
        biasZ4[q]  = (b_ih[128 + col] + b_hh[128 + col]) * (-LOG2E);
        biasXN4[q] = b_ih[256 + col] * (2.0f * LOG2E);
        biasHN4[q] = b_hh[256 + col] * (2.0f * LOG2E);
    }

    __syncthreads();   // sidx ready, h zeroed

    // ---- staging: 2 units/thread; unit = (row, even k0) covering k0,k0+1 ----
    int rowu[2], k0u[2], isx[2];
    const float* pa[2]; const float* pb[2];
#pragma unroll
    for (int un = 0; un < 2; ++un) {
        int u  = tid + un * NTHR;
        int r  = u >> 6;
        int k0 = (u & 63) << 1;
        rowu[un] = r; k0u[un] = k0;
        if (k0 < DIMC) {
            isx[un] = 1;
            pa[un] = x + ((size_t)(bbase + r) * DIMC + k0) * T_;
            pb[un] = pa[un] + T_;
        } else {
            isx[un] = 0;
            int d = k0 - DIMC;
            pa[un] = slist + ((size_t)d       * CS_ + sidx[(r << 6) + d])     * S_;
            pb[un] = slist + ((size_t)(d + 1) * CS_ + sidx[(r << 6) + d + 1]) * S_;
        }
    }

    f32x4 sa[2][2], sb[2][2];   // 8 timesteps x 2 k per thread

    auto issue = [&](int t0) {
#pragma unroll
        for (int un = 0; un < 2; ++un) {
            if (isx[un] && t0 + TCH - 1 > T_ - 1) {   // x tail clamp (t0 = 248 only)
#pragma unroll
                for (int g = 0; g < 2; ++g) {
                    f32x4 va, vb;
#pragma unroll
                    for (int e = 0; e < 4; ++e) {
                        int tt = imin(t0 + g * 4 + e, T_ - 1);
                        va[e] = pa[un][tt]; vb[e] = pb[un][tt];
                    }
                    sa[un][g] = va; sb[un][g] = vb;
                }
            } else {
#pragma unroll
                for (int g = 0; g < 2; ++g) {
                    f32x4 va, vb;
                    __builtin_memcpy(&va, pa[un] + t0 + g * 4, 16);
                    __builtin_memcpy(&vb, pb[un] + t0 + g * 4, 16);
                    sa[un][g] = va; sb[un][g] = vb;
                }
            }
        }
    };

    auto commit = [&](int buf) {
        unsigned short* dst = shx + buf * (TCH * MROWS * XSX);
#pragma unroll
        for (int un = 0; un < 2; ++un) {
#pragma unroll
            for (int g = 0; g < 2; ++g) {
#pragma unroll
                for (int e = 0; e < 4; ++e) {
                    int t = g * 4 + e;
                    unsigned pk = cvt_pk_bf16(sa[un][g][e], sb[un][g][e]);
                    *(unsigned*)&dst[(t * MROWS + rowu[un]) * XSX + k0u[un]] = pk;
                }
            }
        }
    };

    int cur = 0;
    float hprev[4] = {0.f, 0.f, 0.f, 0.f};   // h_old at (row=l15, cols c0col+q)
    const f32x4 Z = {0.f, 0.f, 0.f, 0.f};

    f32x4 xg[2][3];   // [step][gate], bias-seeded, pre-scaled

    // batch x-part of gates for 2 steps (independent MFMAs, off critical path)
    auto xg2 = [&](int buf, int tb, int nt) {
        const unsigned short* base = shx + buf * (TCH * MROWS * XSX);
#pragma unroll
        for (int tt = 0; tt < 2; ++tt) {
            if (tt >= nt) break;
            const unsigned short* xp = base + ((tb + tt) * MROWS + l15) * XSX + (l4 << 3);
            bf16x8 a[4];
#pragma unroll
            for (int kb = 0; kb < 4; ++kb) a[kb] = *(const bf16x8*)(xp + kb * 32);
            f32x4 r = biasR4, z = biasZ4, n = biasXN4;
#pragma unroll
            for (int kb = 0; kb < 4; ++kb) {
                r = __builtin_amdgcn_mfma_f32_16x16x32_bf16(wih[0][kb], a[kb], r, 0, 0, 0);
                z = __builtin_amdgcn_mfma_f32_16x16x32_bf16(wih[1][kb], a[kb], z, 0, 0, 0);
                n = __builtin_amdgcn_mfma_f32_16x16x32_bf16(wih[2][kb], a[kb], n, 0, 0, 0);
            }
            xg[tt][0] = r; xg[tt][1] = z; xg[tt][2] = n;
        }
    };

    auto recur = [&](int st) {
        const unsigned short* hp = shh + cur * HSZ + l15 * XSH + (l4 << 3);
        bf16x8 h0 = *(const bf16x8*)(hp);
        bf16x8 h1 = *(const bf16x8*)(hp + 32);
        bf16x8 h2 = *(const bf16x8*)(hp + 64);
        bf16x8 h3 = *(const bf16x8*)(hp + 96);
        // 2+2 split chains; A=weights, B=h  ->  D: row=gate-col quad, col=batch row
        f32x4 arA = __builtin_amdgcn_mfma_f32_16x16x32_bf16(whh[0][0], h0, xg[st][0], 0, 0, 0);
        f32x4 azA = __builtin_amdgcn_mfma_f32_16x16x32_bf16(whh[1][0], h0, xg[st][1], 0, 0, 0);
        f32x4 anA = __builtin_amdgcn_mfma_f32_16x16x32_bf16(whh[2][0], h0, biasHN4,   0, 0, 0);
        f32x4 arB = __builtin_amdgcn_mfma_f32_16x16x32_bf16(whh[0][2], h2, Z, 0, 0, 0);
        f32x4 azB = __builtin_amdgcn_mfma_f32_16x16x32_bf16(whh[1][2], h2, Z, 0, 0, 0);
        f32x4 anB = __builtin_amdgcn_mfma_f32_16x16x32_bf16(whh[2][2], h2, Z, 0, 0, 0);
        arA = __builtin_amdgcn_mfma_f32_16x16x32_bf16(whh[0][1], h1, arA, 0, 0, 0);
        azA = __builtin_amdgcn_mfma_f32_16x16x32_bf16(whh[1][1], h1, azA, 0, 0, 0);
        anA = __builtin_amdgcn_mfma_f32_16x16x32_bf16(whh[2][1], h1, anA, 0, 0, 0);
        arB = __builtin_amdgcn_mfma_f32_16x16x32_bf16(whh[0][3], h3, arB, 0, 0, 0);
        azB = __builtin_amdgcn_mfma_f32_16x16x32_bf16(whh[1][3], h3, azB, 0, 0, 0);
        anB = __builtin_amdgcn_mfma_f32_16x16x32_bf16(whh[2][3], h3, anB, 0, 0, 0);
        float hn[4];
#pragma unroll
        for (int q = 0; q < 4; ++q) {
            float r    = fast_rcp(1.0f + EXP2(arA[q] + arB[q]));   // args pre-scaled by -log2e
            float z    = fast_rcp(1.0f + EXP2(azA[q] + azB[q]));
            float narg = __builtin_fmaf(r, anA[q] + anB[q], xg[st][2][q]);  // pre-scaled 2log2e
            float tn   = __builtin_fmaf(-2.0f, fast_rcp(1.0f + EXP2(narg)), 1.0f);
            hn[q] = __builtin_fmaf(z, hprev[q] - tn, tn);
            hprev[q] = hn[q];
        }
        // contiguous b64 write: row l15, cols c0col..c0col+3
        unsigned p0 = cvt_pk_bf16(hn[0], hn[1]);
        unsigned p1 = cvt_pk_bf16(hn[2], hn[3]);
        unsigned long long pk = (unsigned long long)p0 | ((unsigned long long)p1 << 32);
        *(unsigned long long*)&shh[(cur ^ 1) * HSZ + l15 * XSH + c0col] = pk;
        bar_lgkm();
        cur ^= 1;
    };

    // ---- prologue: stage chunk 0 ----
    issue(0);
    commit(0);
    __syncthreads();

    // ---- main: 31 full chunks of 8 steps (t = 0..247) ----
    for (int c = 0; c < 31; ++c) {
        issue((c + 1) * TCH);           // prefetch; raw barriers keep loads in flight
        const int bx = c & 1;
#pragma unroll
        for (int sb = 0; sb < 4; ++sb) {
            xg2(bx, sb * 2, 2);
            recur(0); recur(1);
        }
        commit((c + 1) & 1);
        bar_lgkm();
    }
    // ---- tail chunk: 7 steps (t = 248..254), buffer 1 ----
    xg2(1, 0, 2); recur(0); recur(1);
    xg2(1, 2, 2); recur(0); recur(1);
    xg2(1, 4, 2); recur(0); recur(1);
    xg2(1, 6, 1); recur(0);

    // ================= fused MLP epilogue (LDS-resident weights) =================
    float* wl = (float*)smem;   // x/h regions dead; sidx (>= OFF_IDX) preserved

    for (int i = tid; i < 8192; i += NTHR) wl[OW1 + (i >> 7) * 129 + (i & 127)] = W1[i];
    for (int i = tid; i < 2048; i += NTHR) wl[OW2 + (i >> 6) * 65  + (i & 63)]  = W2[i];
    for (int i = tid; i < 512;  i += NTHR) wl[OW3 + (i >> 5) * 33  + (i & 31)]  = W3[i];
    for (int i = tid; i < 5120; i += NTHR) wl[OWL + (i / 80) * 81  + (i % 80)]  = Wl[i];
#pragma unroll
    for (int q = 0; q < 4; ++q)
        wl[OHF + l15 * 128 + c0col + q] = hprev[q];     // row = l15, col = c0col+q
    __syncthreads();

    // wave wv handles batch rows 2*wv, 2*wv+1
    for (int mloc = 0; mloc < 2; ++mloc) {
        const int m = (wv << 1) + mloc;
        {
            float s = b1[lane];
            const float* w = wl + OW1 + lane * 129;
            for (int k = 0; k < 128; ++k) s += wl[OHF + m * 128 + k] * w[k];
            wl[OS1 + wv * 64 + lane] = leaky(s);
        }
        __syncthreads();
        if (lane < 32) {
            float s = b2[lane];
            const float* w = wl + OW2 + lane * 65;
            for (int k = 0; k < 64; ++k) s += wl[OS1 + wv * 64 + k] * w[k];
            wl[OS2 + wv * 32 + lane] = leaky(s);
        } else {
            int d = lane - 32;
            wl[OSL + wv * 64 + d]      = slist[((size_t)d        * CS_ + sidx[(m << 6) + d])      * S_ + (S_ - 1)];
            wl[OSL + wv * 64 + d + 32] = slist[((size_t)(d + 32) * CS_ + sidx[(m << 6) + d + 32]) * S_ + (S_ - 1)];
        }
        __syncthreads();
        if (lane < 16) {
            float s = b3[lane];
            const float* w = wl + OW3 + lane * 33;
            for (int k = 0; k < 32; ++k) s += wl[OS2 + wv * 32 + k] * w[k];
            wl[OS3 + wv * 16 + lane] = leaky(s);
        }
        __syncthreads();
        {
            float s = bl[lane];
            const float* w = wl + OWL + lane * 81;
#pragma unroll
            for (int i = 0; i < 16; ++i) s += wl[OS3 + wv * 16 + i] * w[i];
            for (int d = 0; d < 64; ++d) s += wl[OSL + wv * 64 + d] * w[16 + d];
            out[(size_t)(bbase + m) * DIMC + lane] = leaky(s);
        }
        __syncthreads();
    }
}

extern "C" void kernel_launch(void* const* d_in, const int* in_sizes, int n_in,
                              void* d_out, int out_size, void* d_ws, size_t ws_size,
                              hipStream_t stream) {
    (void)in_sizes; (void)n_in; (void)out_size; (void)d_ws; (void)ws_size;
    const float* x       = (const float*)d_in[0];
    const int*   snippet = (const int*)  d_in[1];
    const float* slist   = (const float*)d_in[2];
    const float* W_ih    = (const float*)d_in[3];
    const float* W_hh    = (const float*)d_in[4];
    const float* b_ih    = (const float*)d_in[5];
    const float* b_hh    = (const float*)d_in[6];
    const float* W1      = (const float*)d_in[7];
    const float* b1      = (const float*)d_in[8];
    const float* W2      = (const float*)d_in[9];
    const float* b2      = (const float*)d_in[10];
    const float* W3      = (const float*)d_in[11];
    const float* b3      = (const float*)d_in[12];
    const float* Wl      = (const float*)d_in[13];
    const float* bl      = (const float*)d_in[14];
    float* out = (float*)d_out;

    hipLaunchKernelGGL(gru_fused, dim3(NBLK), dim3(NTHR), 0, stream,
                       x, snippet, slist, W_ih, W_hh, b_ih, b_hh,
                       W1, b1, W2, b2, W3, b3, Wl, bl, out);
}